// Round 10
// baseline (19.805 us; speedup 1.0000x reference)
//
#include <hip/hip_runtime.h>

#define KN    4096
#define LTOT  6
#define BATCH 8192
#define NT    1024
#define NITER (KN / NT)          // 4
#define NPAT  4
#define RPT   (BATCH / NT)       // 8 rows per thread in scatter phase

// Per-neuron operands:
//   pidx[l*KN+k]  = (ia*4) | ((ib*4) << 16)   -- byte offsets into float LDS buffer
//   pcoef[l*KN+k] = {c1, ca, cb, cab} fp32
__global__ __launch_bounds__(256) void pack_kernel(const float* __restrict__ w0,
                                                   const float* __restrict__ ws,
                                                   const int* __restrict__ idx0,
                                                   const int* __restrict__ idxs,
                                                   unsigned* __restrict__ pidx,
                                                   float4* __restrict__ pcoef) {
    const float TAB[16][4] = {
        {0.f, 0.f, 0.f, 0.f}, {0.f, 0.f, 0.f, 1.f}, {0.f, 1.f, 0.f,-1.f}, {0.f, 1.f, 0.f, 0.f},
        {0.f, 0.f, 1.f,-1.f}, {0.f, 0.f, 1.f, 0.f}, {0.f, 1.f, 1.f,-2.f}, {0.f, 1.f, 1.f,-1.f},
        {1.f,-1.f,-1.f, 1.f}, {1.f,-1.f,-1.f, 2.f}, {1.f, 0.f,-1.f, 0.f}, {1.f, 0.f,-1.f, 1.f},
        {1.f,-1.f, 0.f, 0.f}, {1.f,-1.f, 0.f, 1.f}, {1.f, 0.f, 0.f,-1.f}, {1.f, 0.f, 0.f, 0.f}
    };
    int gid = blockIdx.x * 256 + threadIdx.x;
    if (gid >= LTOT * KN) return;
    int l = gid >> 12;
    int k = gid & (KN - 1);
    const float* w = (l == 0) ? (w0 + k * 16) : (ws + ((size_t)((l - 1) * KN + k) << 4));
    float wv[16];
    float m = -1e30f;
#pragma unroll
    for (int j = 0; j < 16; ++j) { wv[j] = w[j]; m = fmaxf(m, wv[j]); }
    float s = 0.f;
#pragma unroll
    for (int j = 0; j < 16; ++j) { wv[j] = __expf(wv[j] - m); s += wv[j]; }
    float inv = 1.0f / s;
    float c0 = 0.f, c1 = 0.f, c2 = 0.f, c3 = 0.f;
#pragma unroll
    for (int j = 0; j < 16; ++j) {
        c0 += wv[j] * TAB[j][0];
        c1 += wv[j] * TAB[j][1];
        c2 += wv[j] * TAB[j][2];
        c3 += wv[j] * TAB[j][3];
    }
    pcoef[gid] = make_float4(c0 * inv, c1 * inv, c2 * inv, c3 * inv);

    int ia, ib;
    if (l == 0) { ia = idx0[k];                            ib = idx0[KN + k]; }
    else        { ia = idxs[(size_t)(l - 1) * 2 * KN + k]; ib = idxs[(size_t)(l - 1) * 2 * KN + KN + k]; }
    pidx[gid] = ((unsigned)ia * 4u) | (((unsigned)ib * 4u) << 16);
}

// One block per input pattern p in {0..3}: f0 = p&1, f1 = (p>>1)&1.
// Evaluates the full fp32 network for its pattern, then scatters the
// resulting (cls0, cls1) pair to every batch row whose pattern == p.
// The 4 blocks cover disjoint row sets -> full output coverage, no
// cross-block dependency.
__global__ __launch_bounds__(NT) void netscatter_kernel(const float* __restrict__ x,
                                                        const unsigned* __restrict__ pidx,
                                                        const float4* __restrict__ pcoef,
                                                        float2* __restrict__ out) {
    __shared__ float hbuf[2][KN];        // 32 KB
    __shared__ float red[NT / 64][2];

    const int t = threadIdx.x;
    const int p = blockIdx.x;
    const float f0 = (p & 1) ? 1.f : 0.f;
    const float f1 = (p & 2) ? 1.f : 0.f;

    // Layer 0: 2 -> K
#pragma unroll
    for (int i = 0; i < NITER; ++i) {
        int k = t + i * NT;
        unsigned px = pidx[k];
        float4   c  = pcoef[k];
        float A = (px & 0xffffu) ? f1 : f0;
        float B = (px >> 16)     ? f1 : f0;
        hbuf[0][k] = fmaf(fmaf(c.w, B, c.y), A, fmaf(c.z, B, c.x));
    }
    __syncthreads();

    // Layers 1..5: K -> K, ping-pong
#pragma unroll
    for (int l = 1; l < LTOT; ++l) {
        const unsigned* __restrict__ pi = pidx  + (size_t)l * KN;
        const float4*   __restrict__ pc = pcoef + (size_t)l * KN;
        const char* hs = (const char*)&hbuf[(l + 1) & 1][0];
        float*      hd = &hbuf[l & 1][0];
#pragma unroll
        for (int i = 0; i < NITER; ++i) {
            int k = t + i * NT;
            unsigned px = pi[k];
            float4   c  = pc[k];
            float A = *(const float*)(hs + (px & 0xffffu));
            float B = *(const float*)(hs + (px >> 16));
            hd[k] = fmaf(fmaf(c.w, B, c.y), A, fmaf(c.z, B, c.x));
        }
        __syncthreads();
    }

    // GroupSum: final activations in hbuf[1] (layer 5 writes hbuf[5&1]).
    float acc0 = 0.f, acc1 = 0.f;
#pragma unroll
    for (int i = 0; i < NITER; ++i) {
        int k = t + i * NT;
        float v = hbuf[1][k];
        if (k < KN / 2) acc0 += v; else acc1 += v;
    }
#pragma unroll
    for (int off = 32; off > 0; off >>= 1) {
        acc0 += __shfl_down(acc0, off);
        acc1 += __shfl_down(acc1, off);
    }
    int wave = t >> 6, lane = t & 63;
    if (lane == 0) { red[wave][0] = acc0; red[wave][1] = acc1; }
    __syncthreads();
    if (t == 0) {
        float s0 = 0.f, s1 = 0.f;
#pragma unroll
        for (int w = 0; w < NT / 64; ++w) { s0 += red[w][0]; s1 += red[w][1]; }
        red[0][0] = s0; red[0][1] = s1;
    }
    __syncthreads();
    const float2 tbl = make_float2(red[0][0], red[0][1]);

    // Scatter: write tbl to every row whose pattern == p.
    const float2* __restrict__ x2 = (const float2*)x;
#pragma unroll
    for (int i = 0; i < RPT; ++i) {
        int b = t + i * NT;
        float2 xv = x2[b];
        int pat = (xv.x > 0.f ? 1 : 0) | (xv.y > 0.f ? 2 : 0);
        if (pat == p) out[b] = tbl;
    }
}

extern "C" void kernel_launch(void* const* d_in, const int* in_sizes, int n_in,
                              void* d_out, int out_size, void* d_ws, size_t ws_size,
                              hipStream_t stream) {
    const float* x    = (const float*)d_in[0];
    const float* w0   = (const float*)d_in[1];
    const float* ws   = (const float*)d_in[2];
    const int*   idx0 = (const int*)d_in[3];
    const int*   idxs = (const int*)d_in[4];
    float*       out  = (float*)d_out;

    float4*   pcoef = (float4*)d_ws;                    // 384 KB
    unsigned* pidx  = (unsigned*)(pcoef + LTOT * KN);   //  96 KB

    pack_kernel<<<(LTOT * KN + 255) / 256, 256, 0, stream>>>(w0, ws, idx0, idxs, pidx, pcoef);
    netscatter_kernel<<<NPAT, NT, 0, stream>>>(x, pidx, pcoef, (float2*)out);
}

// Round 12
// 18.967 us; speedup vs baseline: 1.0442x; 1.0442x over previous
//
#include <hip/hip_runtime.h>
#include <hip/hip_fp16.h>

#define KN    4096
#define LTOT  6
#define BATCH 8192
#define NT    1024
#define NITER (KN / NT)          // 4
#define NPAT  4
#define RPT   (BATCH / NT)       // 8 rows/thread in scatter phase

// SoA operand arrays (u32 each), one entry per neuron per layer:
//   gidx[l*KN+k] = (ia*4) | ((ib*4) << 16)   -- byte offsets into f32 activation LDS
//   gca [l*KN+k] = half2(c1, ca)
//   gcb [l*KN+k] = half2(cb, cab)
__global__ __launch_bounds__(256) void pack_kernel(const float* __restrict__ w0,
                                                   const float* __restrict__ ws,
                                                   const int* __restrict__ idx0,
                                                   const int* __restrict__ idxs,
                                                   unsigned* __restrict__ gidx,
                                                   unsigned* __restrict__ gca,
                                                   unsigned* __restrict__ gcb) {
    const float TAB[16][4] = {
        {0.f, 0.f, 0.f, 0.f}, {0.f, 0.f, 0.f, 1.f}, {0.f, 1.f, 0.f,-1.f}, {0.f, 1.f, 0.f, 0.f},
        {0.f, 0.f, 1.f,-1.f}, {0.f, 0.f, 1.f, 0.f}, {0.f, 1.f, 1.f,-2.f}, {0.f, 1.f, 1.f,-1.f},
        {1.f,-1.f,-1.f, 1.f}, {1.f,-1.f,-1.f, 2.f}, {1.f, 0.f,-1.f, 0.f}, {1.f, 0.f,-1.f, 1.f},
        {1.f,-1.f, 0.f, 0.f}, {1.f,-1.f, 0.f, 1.f}, {1.f, 0.f, 0.f,-1.f}, {1.f, 0.f, 0.f, 0.f}
    };
    int gid = blockIdx.x * 256 + threadIdx.x;
    if (gid >= LTOT * KN) return;
    int l = gid >> 12;
    int k = gid & (KN - 1);
    const float* w = (l == 0) ? (w0 + k * 16) : (ws + ((size_t)((l - 1) * KN + k) << 4));
    float wv[16];
    float m = -1e30f;
#pragma unroll
    for (int j = 0; j < 16; ++j) { wv[j] = w[j]; m = fmaxf(m, wv[j]); }
    float s = 0.f;
#pragma unroll
    for (int j = 0; j < 16; ++j) { wv[j] = __expf(wv[j] - m); s += wv[j]; }
    float inv = 1.0f / s;
    float c0 = 0.f, c1 = 0.f, c2 = 0.f, c3 = 0.f;
#pragma unroll
    for (int j = 0; j < 16; ++j) {
        c0 += wv[j] * TAB[j][0];
        c1 += wv[j] * TAB[j][1];
        c2 += wv[j] * TAB[j][2];
        c3 += wv[j] * TAB[j][3];
    }
    __half2 ya = __floats2half2_rn(c0 * inv, c1 * inv);
    __half2 yb = __floats2half2_rn(c2 * inv, c3 * inv);

    int ia, ib;
    if (l == 0) { ia = idx0[k];                            ib = idx0[KN + k]; }
    else        { ia = idxs[(size_t)(l - 1) * 2 * KN + k]; ib = idxs[(size_t)(l - 1) * 2 * KN + KN + k]; }

    gidx[gid] = ((unsigned)ia * 4u) | (((unsigned)ib * 4u) << 16);
    gca[gid]  = *(const unsigned*)&ya;
    gcb[gid]  = *(const unsigned*)&yb;
}

#define WAITVM(N) do { asm volatile("s_waitcnt vmcnt(" #N ")" ::: "memory"); \
                       __builtin_amdgcn_sched_barrier(0); } while (0)
#define LGKM_BAR() do { asm volatile("s_waitcnt lgkmcnt(0)" ::: "memory");  \
                        __builtin_amdgcn_s_barrier();                       \
                        asm volatile("" ::: "memory"); } while (0)

// Issue layer L's operands into the [L&1] LDS buffers via size-4 async DMA
// (HW-verified width). Each wave's region is private: dest = uniform base,
// HW writes at base + lane*4; src = per-lane address. 12 vmem instrs total.
#define ISSUE(L) do {                                                               \
    const unsigned* __restrict__ si_ = gidx + (size_t)(L) * KN;                     \
    const unsigned* __restrict__ sa_ = gca + (size_t)(L) * KN;                      \
    const unsigned* __restrict__ sb_ = gcb + (size_t)(L) * KN;                      \
    _Pragma("unroll")                                                               \
    for (int i = 0; i < NITER; ++i) {                                               \
        int o_ = i * NT + w64;                                                      \
        __builtin_amdgcn_global_load_lds(                                           \
            (const __attribute__((address_space(1))) void*)(si_ + o_ + lane),       \
            (__attribute__((address_space(3))) void*)&oidx[(L) & 1][o_], 4, 0, 0);  \
        __builtin_amdgcn_global_load_lds(                                           \
            (const __attribute__((address_space(1))) void*)(sa_ + o_ + lane),       \
            (__attribute__((address_space(3))) void*)&ocA[(L) & 1][o_], 4, 0, 0);   \
        __builtin_amdgcn_global_load_lds(                                           \
            (const __attribute__((address_space(1))) void*)(sb_ + o_ + lane),       \
            (__attribute__((address_space(3))) void*)&ocB[(L) & 1][o_], 4, 0, 0);   \
    }                                                                               \
    asm volatile("" ::: "memory");                                                  \
} while (0)

// Layers 1..4: operands from [L&1] buffers, gather hbuf[(L+1)&1], write hbuf[L&1].
#define COMPUTE_MID(L) do {                                                    \
    const char* hs_ = (const char*)&hbuf[((L) + 1) & 1][0];                    \
    float*      hd_ = &hbuf[(L) & 1][0];                                       \
    _Pragma("unroll")                                                          \
    for (int i = 0; i < NITER; ++i) {                                          \
        int k_ = t + i * NT;                                                   \
        unsigned px_ = oidx[(L) & 1][k_];                                      \
        float2 cA_ = __half22float2(*(const __half2*)&ocA[(L) & 1][k_]);       \
        float2 cB_ = __half22float2(*(const __half2*)&ocB[(L) & 1][k_]);       \
        float A_ = *(const float*)(hs_ + (px_ & 0xffffu));                     \
        float B_ = *(const float*)(hs_ + (px_ >> 16));                         \
        hd_[k_] = fmaf(fmaf(cB_.y, B_, cA_.y), A_, fmaf(cB_.x, B_, cA_.x));    \
    }                                                                          \
} while (0)

// One block per input pattern p: evaluates the network with a depth-2
// operand DMA pipeline (counted vmcnt), then scatters its pattern's rows.
__global__ __launch_bounds__(NT) void netscatter_kernel(const float* __restrict__ x,
                                                        const unsigned* __restrict__ gidx,
                                                        const unsigned* __restrict__ gca,
                                                        const unsigned* __restrict__ gcb,
                                                        float2* __restrict__ out) {
    __shared__ unsigned oidx[2][KN];     // 32 KB
    __shared__ unsigned ocA[2][KN];      // 32 KB
    __shared__ unsigned ocB[2][KN];      // 32 KB
    __shared__ float    hbuf[2][KN];     // 32 KB
    __shared__ float    red[NT / 64][2];

    const int t    = threadIdx.x;
    const int lane = t & 63;
    const int w64  = t & ~63;            // wave base (uniform per wave)
    const int p    = blockIdx.x;
    const float f0 = (p & 1) ? 1.f : 0.f;
    const float f1 = (p & 2) ? 1.f : 0.f;

    // Prefetch the scatter-phase x rows into registers (oldest vmem entries,
    // retire before the counted DMA waits ever look at them).
    const float2* __restrict__ x2 = (const float2*)x;
    float2 xr[RPT];
#pragma unroll
    for (int i = 0; i < RPT; ++i) xr[i] = x2[t + i * NT];

    ISSUE(0);
    ISSUE(1);

    // ---- Layer 0: 2 -> K (operands from buffers[0]) ----
    WAITVM(12);
    {
#pragma unroll
        for (int i = 0; i < NITER; ++i) {
            int k = t + i * NT;
            unsigned px = oidx[0][k];
            float2 cA = __half22float2(*(const __half2*)&ocA[0][k]);
            float2 cB = __half22float2(*(const __half2*)&ocB[0][k]);
            float A = (px & 0xffffu) ? f1 : f0;
            float B = (px >> 16)     ? f1 : f0;
            hbuf[0][k] = fmaf(fmaf(cB.y, B, cA.y), A, fmaf(cB.x, B, cA.x));
        }
    }
    ISSUE(2);
    LGKM_BAR();

    WAITVM(12);  COMPUTE_MID(1);  ISSUE(3);  LGKM_BAR();
    WAITVM(12);  COMPUTE_MID(2);  ISSUE(4);  LGKM_BAR();
    WAITVM(12);  COMPUTE_MID(3);  ISSUE(5);  LGKM_BAR();
    WAITVM(12);  COMPUTE_MID(4);  LGKM_BAR();

    // ---- Layer 5 fused with GroupSum (reads hbuf[0], no write-back) ----
    WAITVM(0);
    float acc0 = 0.f, acc1 = 0.f;
    {
        const char* hs = (const char*)&hbuf[0][0];
#pragma unroll
        for (int i = 0; i < NITER; ++i) {
            int k = t + i * NT;
            unsigned px = oidx[1][k];
            float2 cA = __half22float2(*(const __half2*)&ocA[1][k]);
            float2 cB = __half22float2(*(const __half2*)&ocB[1][k]);
            float A = *(const float*)(hs + (px & 0xffffu));
            float B = *(const float*)(hs + (px >> 16));
            float o = fmaf(fmaf(cB.y, B, cA.y), A, fmaf(cB.x, B, cA.x));
            if (i < NITER / 2) acc0 += o; else acc1 += o;   // class = (k >= 2048)
        }
    }
#pragma unroll
    for (int off = 32; off > 0; off >>= 1) {
        acc0 += __shfl_down(acc0, off);
        acc1 += __shfl_down(acc1, off);
    }
    int wave = t >> 6;
    if (lane == 0) { red[wave][0] = acc0; red[wave][1] = acc1; }
    __syncthreads();
    if (t == 0) {
        float s0 = 0.f, s1 = 0.f;
#pragma unroll
        for (int w = 0; w < NT / 64; ++w) { s0 += red[w][0]; s1 += red[w][1]; }
        red[0][0] = s0; red[0][1] = s1;
    }
    __syncthreads();
    const float2 tbl = make_float2(red[0][0], red[0][1]);

    // ---- Scatter: write tbl to every row whose pattern == p ----
#pragma unroll
    for (int i = 0; i < RPT; ++i) {
        int b = t + i * NT;
        int pat = (xr[i].x > 0.f ? 1 : 0) | (xr[i].y > 0.f ? 2 : 0);
        if (pat == p) out[b] = tbl;
    }
}

extern "C" void kernel_launch(void* const* d_in, const int* in_sizes, int n_in,
                              void* d_out, int out_size, void* d_ws, size_t ws_size,
                              hipStream_t stream) {
    const float* x    = (const float*)d_in[0];
    const float* w0   = (const float*)d_in[1];
    const float* ws   = (const float*)d_in[2];
    const int*   idx0 = (const int*)d_in[3];
    const int*   idxs = (const int*)d_in[4];
    float*       out  = (float*)d_out;

    unsigned* gidx = (unsigned*)d_ws;            // 96 KB
    unsigned* gca  = gidx + LTOT * KN;           // 96 KB
    unsigned* gcb  = gca  + LTOT * KN;           // 96 KB

    pack_kernel<<<(LTOT * KN + 255) / 256, 256, 0, stream>>>(w0, ws, idx0, idxs,
                                                             gidx, gca, gcb);
    netscatter_kernel<<<NPAT, NT, 0, stream>>>(x, gidx, gca, gcb, (float2*)out);
}

// Round 13
// 18.669 us; speedup vs baseline: 1.0608x; 1.0159x over previous
//
#include <hip/hip_runtime.h>
#include <hip/hip_fp16.h>

#define KN    4096
#define LTOT  6
#define BATCH 8192
#define NT    1024
#define NITER (KN / NT)          // 4
#define NPAT  4
#define RPT   (BATCH / NT)       // 8 rows/thread in scatter phase

// Packed operand record, 12 B/neuron (loaded as one dwordx3 into VGPRs):
//   x = (ia*4) | ((ib*4) << 16)   -- byte offsets into f32 activation LDS
//   y = half2(c1, ca)
//   z = half2(cb, cab)
__global__ __launch_bounds__(256) void pack_kernel(const float* __restrict__ w0,
                                                   const float* __restrict__ ws,
                                                   const int* __restrict__ idx0,
                                                   const int* __restrict__ idxs,
                                                   uint3* __restrict__ pk) {
    const float TAB[16][4] = {
        {0.f, 0.f, 0.f, 0.f}, {0.f, 0.f, 0.f, 1.f}, {0.f, 1.f, 0.f,-1.f}, {0.f, 1.f, 0.f, 0.f},
        {0.f, 0.f, 1.f,-1.f}, {0.f, 0.f, 1.f, 0.f}, {0.f, 1.f, 1.f,-2.f}, {0.f, 1.f, 1.f,-1.f},
        {1.f,-1.f,-1.f, 1.f}, {1.f,-1.f,-1.f, 2.f}, {1.f, 0.f,-1.f, 0.f}, {1.f, 0.f,-1.f, 1.f},
        {1.f,-1.f, 0.f, 0.f}, {1.f,-1.f, 0.f, 1.f}, {1.f, 0.f, 0.f,-1.f}, {1.f, 0.f, 0.f, 0.f}
    };
    int gid = blockIdx.x * 256 + threadIdx.x;
    if (gid >= LTOT * KN) return;
    int l = gid >> 12;
    int k = gid & (KN - 1);
    const float* w = (l == 0) ? (w0 + k * 16) : (ws + ((size_t)((l - 1) * KN + k) << 4));
    const float4* w4 = (const float4*)w;
    float wv[16];
    float4 q0 = w4[0], q1 = w4[1], q2 = w4[2], q3 = w4[3];
    wv[0]=q0.x; wv[1]=q0.y; wv[2]=q0.z; wv[3]=q0.w;
    wv[4]=q1.x; wv[5]=q1.y; wv[6]=q1.z; wv[7]=q1.w;
    wv[8]=q2.x; wv[9]=q2.y; wv[10]=q2.z; wv[11]=q2.w;
    wv[12]=q3.x; wv[13]=q3.y; wv[14]=q3.z; wv[15]=q3.w;
    float m = -1e30f;
#pragma unroll
    for (int j = 0; j < 16; ++j) m = fmaxf(m, wv[j]);
    float s = 0.f;
#pragma unroll
    for (int j = 0; j < 16; ++j) { wv[j] = __expf(wv[j] - m); s += wv[j]; }
    float inv = 1.0f / s;
    float c0 = 0.f, c1 = 0.f, c2 = 0.f, c3 = 0.f;
#pragma unroll
    for (int j = 0; j < 16; ++j) {
        c0 += wv[j] * TAB[j][0];
        c1 += wv[j] * TAB[j][1];
        c2 += wv[j] * TAB[j][2];
        c3 += wv[j] * TAB[j][3];
    }
    __half2 ya = __floats2half2_rn(c0 * inv, c1 * inv);
    __half2 yb = __floats2half2_rn(c2 * inv, c3 * inv);

    int ia, ib;
    if (l == 0) { ia = idx0[k];                            ib = idx0[KN + k]; }
    else        { ia = idxs[(size_t)(l - 1) * 2 * KN + k]; ib = idxs[(size_t)(l - 1) * 2 * KN + KN + k]; }

    uint3 e;
    e.x = ((unsigned)ia * 4u) | (((unsigned)ib * 4u) << 16);
    e.y = *(const unsigned*)&ya;
    e.z = *(const unsigned*)&yb;
    pk[gid] = e;
}

// One block per input pattern p in {0..3}. All 24 operand records/thread are
// loaded into registers up front (one overlapped burst, pinned by keep-alive
// asm so the compiler cannot sink them into the layer loop). The layer loop
// touches LDS only for the 2 activation gathers + 1 write per neuron.
__global__ __launch_bounds__(NT, 4) void netscatter_kernel(const float* __restrict__ x,
                                                           const uint3* __restrict__ pk,
                                                           float2* __restrict__ out) {
    __shared__ float hbuf[2][KN];        // 32 KB activation ping-pong
    __shared__ float red[NT / 64][2];

    const int t = threadIdx.x;
    const int p = blockIdx.x;
    const float f0 = (p & 1) ? 1.f : 0.f;
    const float f1 = (p & 2) ? 1.f : 0.f;

    // ---- Operand burst: 24 dwordx3 loads, all issued before any use ----
    uint3 op[LTOT][NITER];
#pragma unroll
    for (int l = 0; l < LTOT; ++l)
#pragma unroll
        for (int i = 0; i < NITER; ++i)
            op[l][i] = pk[(size_t)l * KN + i * NT + t];

    // Scatter-phase x rows (tail work, issued in the same burst).
    const float2* __restrict__ x2 = (const float2*)x;
    float2 xr[RPT];
#pragma unroll
    for (int i = 0; i < RPT; ++i) xr[i] = x2[t + i * NT];

    // Keep-alive: force all operand loads materialized HERE (anti-sink).
#pragma unroll
    for (int l = 0; l < LTOT; ++l)
#pragma unroll
        for (int i = 0; i < NITER; ++i)
            asm volatile("" :: "v"(op[l][i].x), "v"(op[l][i].y), "v"(op[l][i].z));

    // ---- Layer 0: 2 -> K, writes hbuf[0] ----
#pragma unroll
    for (int i = 0; i < NITER; ++i) {
        int k = t + i * NT;
        unsigned px = op[0][i].x;
        float2 cA = __half22float2(*(const __half2*)&op[0][i].y);
        float2 cB = __half22float2(*(const __half2*)&op[0][i].z);
        float A = (px & 0xffffu) ? f1 : f0;
        float B = (px >> 16)     ? f1 : f0;
        hbuf[0][k] = fmaf(fmaf(cB.y, B, cA.y), A, fmaf(cB.x, B, cA.x));
    }
    __syncthreads();

    // ---- Layers 1..4: K -> K, ping-pong, operands from registers ----
#pragma unroll
    for (int l = 1; l <= 4; ++l) {
        const char* hs = (const char*)&hbuf[(l + 1) & 1][0];
        float*      hd = &hbuf[l & 1][0];
#pragma unroll
        for (int i = 0; i < NITER; ++i) {
            int k = t + i * NT;
            unsigned px = op[l][i].x;
            float2 cA = __half22float2(*(const __half2*)&op[l][i].y);
            float2 cB = __half22float2(*(const __half2*)&op[l][i].z);
            float A = *(const float*)(hs + (px & 0xffffu));
            float B = *(const float*)(hs + (px >> 16));
            hd[k] = fmaf(fmaf(cB.y, B, cA.y), A, fmaf(cB.x, B, cA.x));
        }
        __syncthreads();
    }

    // ---- Layer 5 fused with GroupSum (reads hbuf[0], no write-back) ----
    float acc0 = 0.f, acc1 = 0.f;
    {
        const char* hs = (const char*)&hbuf[0][0];
#pragma unroll
        for (int i = 0; i < NITER; ++i) {
            unsigned px = op[5][i].x;
            float2 cA = __half22float2(*(const __half2*)&op[5][i].y);
            float2 cB = __half22float2(*(const __half2*)&op[5][i].z);
            float A = *(const float*)(hs + (px & 0xffffu));
            float B = *(const float*)(hs + (px >> 16));
            float o = fmaf(fmaf(cB.y, B, cA.y), A, fmaf(cB.x, B, cA.x));
            if (i < NITER / 2) acc0 += o; else acc1 += o;   // class = (k >= 2048)
        }
    }
#pragma unroll
    for (int off = 32; off > 0; off >>= 1) {
        acc0 += __shfl_down(acc0, off);
        acc1 += __shfl_down(acc1, off);
    }
    int wave = t >> 6, lane = t & 63;
    if (lane == 0) { red[wave][0] = acc0; red[wave][1] = acc1; }
    __syncthreads();
    if (t == 0) {
        float s0 = 0.f, s1 = 0.f;
#pragma unroll
        for (int w = 0; w < NT / 64; ++w) { s0 += red[w][0]; s1 += red[w][1]; }
        red[0][0] = s0; red[0][1] = s1;
    }
    __syncthreads();
    const float2 tbl = make_float2(red[0][0], red[0][1]);

    // ---- Scatter: write tbl to every row whose pattern == p ----
#pragma unroll
    for (int i = 0; i < RPT; ++i) {
        int b = t + i * NT;
        int pat = (xr[i].x > 0.f ? 1 : 0) | (xr[i].y > 0.f ? 2 : 0);
        if (pat == p) out[b] = tbl;
    }
}

extern "C" void kernel_launch(void* const* d_in, const int* in_sizes, int n_in,
                              void* d_out, int out_size, void* d_ws, size_t ws_size,
                              hipStream_t stream) {
    const float* x    = (const float*)d_in[0];
    const float* w0   = (const float*)d_in[1];
    const float* ws   = (const float*)d_in[2];
    const int*   idx0 = (const int*)d_in[3];
    const int*   idxs = (const int*)d_in[4];
    float*       out  = (float*)d_out;
    uint3*       pk   = (uint3*)d_ws;    // LTOT*KN*12 B = 288 KB scratch

    pack_kernel<<<(LTOT * KN + 255) / 256, 256, 0, stream>>>(w0, ws, idx0, idxs, pk);
    netscatter_kernel<<<NPAT, NT, 0, stream>>>(x, pk, (float2*)out);
}